// Round 1
// baseline (892.574 us; speedup 1.0000x reference)
//
#include <hip/hip_runtime.h>
#include <hip/hip_bf16.h>
#include <math.h>

#define T0 128
#define BN 256           // B*N = 8*32
#define Ff 128
#define Hh 256
#define NODE0 32768      // BN*T0
#define E0 262144        // NODE0*8
#define T1 64
#define NODE1 16384      // BN*T1
#define E1 131072

__device__ __forceinline__ float4 f4max(float4 a, float4 b) {
  return make_float4(fmaxf(a.x,b.x), fmaxf(a.y,b.y), fmaxf(a.z,b.z), fmaxf(a.w,b.w));
}

// data [T, BN, F] -> X0 [bn*T + t, F]
__global__ void k_perm(const float* __restrict__ src, float* __restrict__ dst) {
  int idx = blockIdx.x * 256 + threadIdx.x;   // over NODE0 * (F/4)
  int c4 = idx & 31;        // F/4 = 32
  int r  = idx >> 5;
  int t  = r & (T0 - 1);
  int bn = r >> 7;
  float4 v = ((const float4*)src)[((size_t)t * BN + bn) * 32 + c4];
  ((float4*)dst)[idx] = v;
}

// Wd = W[0:halfK] - W[halfK:2*halfK]   (row-major [2*halfK, 256])
__global__ void k_wd(const float* __restrict__ W, float* __restrict__ Wd, int halfK) {
  int idx = blockIdx.x * 256 + threadIdx.x;   // halfK*256
  Wd[idx] = W[idx] - W[idx + halfK * 256];
}

// Wc [O=256, I=256, K=5] -> Wt [k][i][o]
__global__ void k_wt(const float* __restrict__ Wc, float* __restrict__ Wt) {
  int idx = blockIdx.x * 256 + threadIdx.x;   // 5*256*256
  int o = idx & 255;
  int i = (idx >> 8) & 255;
  int k = idx >> 16;
  Wt[idx] = Wc[(o * 256 + i) * 5 + k];
}

__global__ void k_count(const int* __restrict__ dst, int* __restrict__ cnt, int E) {
  int e = blockIdx.x * 256 + threadIdx.x;
  if (e < E) atomicAdd(&cnt[dst[e]], 1);
}

// exclusive scan of cnt[n] -> off[0..n], also copy into cur
__global__ __launch_bounds__(1024) void k_scan(const int* __restrict__ cnt, int* __restrict__ off,
                                               int* __restrict__ cur, int n) {
  __shared__ int part[1024];
  int tid = threadIdx.x;
  int chunk = n >> 10;
  int base = tid * chunk;
  int s = 0;
  for (int i = 0; i < chunk; ++i) s += cnt[base + i];
  part[tid] = s;
  __syncthreads();
  for (int d = 1; d < 1024; d <<= 1) {
    int v = (tid >= d) ? part[tid - d] : 0;
    __syncthreads();
    part[tid] += v;
    __syncthreads();
  }
  int run = (tid == 0) ? 0 : part[tid - 1];
  for (int i = 0; i < chunk; ++i) {
    off[base + i] = run;
    cur[base + i] = run;
    run += cnt[base + i];
  }
  if (tid == 1023) off[n] = run;
}

__global__ void k_fill(const int* __restrict__ srcIdx, const int* __restrict__ dstIdx,
                       int* __restrict__ cur, int* __restrict__ srcs, int E) {
  int e = blockIdx.x * 256 + threadIdx.x;
  if (e < E) {
    int p = atomicAdd(&cur[dstIdx[e]], 1);
    srcs[p] = srcIdx[e];
  }
}

// per-node segment max over incoming-edge source rows of Bm [*, 256]
__global__ __launch_bounds__(256) void k_maxg(const float* __restrict__ Bm, const int* __restrict__ off,
                                              const int* __restrict__ srcs, float* __restrict__ Mm) {
  int node = blockIdx.x * 4 + (threadIdx.x >> 6);
  int lane = threadIdx.x & 63;
  int b = off[node], e = off[node + 1];
  float4 m = make_float4(-INFINITY, -INFINITY, -INFINITY, -INFINITY);
  for (int i = b; i < e; ++i) {
    int s = srcs[i];
    m = f4max(m, *(const float4*)(Bm + (size_t)s * 256 + lane * 4));
  }
  *(float4*)(Mm + (size_t)node * 256 + lane * 4) = m;
}

// C[M,256] = A[M,K] @ W[K,256]; FUSE: C = relu(A@W + bias + Mrow)
template <bool FUSE>
__global__ __launch_bounds__(256) void k_gemm(const float* __restrict__ A, const float* __restrict__ W,
                                              float* __restrict__ C, int K,
                                              const float* __restrict__ bias,
                                              const float* __restrict__ Mrow) {
  __shared__ float As[16][68];
  __shared__ float Ws[16][64];
  int tid = threadIdx.x;
  int row0 = blockIdx.x * 64;
  int col0 = blockIdx.y * 64;
  int ty = tid >> 4, tx = tid & 15;
  int ar = tid >> 2, ac = (tid & 3) * 4;
  int wr = tid >> 4, wc = (tid & 15) * 4;
  float acc[4][4] = {};
  for (int kb = 0; kb < K; kb += 16) {
    float4 av = *(const float4*)(A + (size_t)(row0 + ar) * K + kb + ac);
    As[ac + 0][ar] = av.x; As[ac + 1][ar] = av.y; As[ac + 2][ar] = av.z; As[ac + 3][ar] = av.w;
    *(float4*)&Ws[wr][wc] = *(const float4*)(W + (size_t)(kb + wr) * 256 + col0 + wc);
    __syncthreads();
#pragma unroll
    for (int kk = 0; kk < 16; ++kk) {
      float a[4], b[4];
#pragma unroll
      for (int i = 0; i < 4; ++i) a[i] = As[kk][ty * 4 + i];
#pragma unroll
      for (int j = 0; j < 4; ++j) b[j] = Ws[kk][tx * 4 + j];
#pragma unroll
      for (int i = 0; i < 4; ++i)
#pragma unroll
        for (int j = 0; j < 4; ++j) acc[i][j] = fmaf(a[i], b[j], acc[i][j]);
    }
    __syncthreads();
  }
#pragma unroll
  for (int i = 0; i < 4; ++i) {
    int r = row0 + ty * 4 + i;
    int c = col0 + tx * 4;
    float4 v = make_float4(acc[i][0], acc[i][1], acc[i][2], acc[i][3]);
    if (FUSE) {
      float4 bv = *(const float4*)(bias + c);
      float4 mv = *(const float4*)(Mrow + (size_t)r * 256 + c);
      v.x = fmaxf(v.x + bv.x + mv.x, 0.f);
      v.y = fmaxf(v.y + bv.y + mv.y, 0.f);
      v.z = fmaxf(v.z + bv.z + mv.z, 0.f);
      v.w = fmaxf(v.w + bv.w + mv.w, 0.f);
    }
    *(float4*)(C + (size_t)r * 256 + c) = v;
  }
}

// temporal conv (k=5, pad=2) + bias + relu + maxpool(2); X [Mrows,256] viewed [BN][Trows][256]
__global__ __launch_bounds__(256) void k_conv(const float* __restrict__ X, const float* __restrict__ Wt,
                                              const float* __restrict__ bc, float* __restrict__ Y,
                                              int Trows) {
  __shared__ float As[16][68];
  __shared__ float Ws[16][64];
  int tid = threadIdx.x;
  int row0 = blockIdx.x * 64;
  int col0 = blockIdx.y * 64;
  int ty = tid >> 4, tx = tid & 15;
  int ar = tid >> 2, ac = (tid & 3) * 4;
  int wr = tid >> 4, wc = (tid & 15) * 4;
  int bnIdx = row0 / Trows;
  int t0 = row0 - bnIdx * Trows;
  const float* Xbn = X + (size_t)bnIdx * Trows * 256;
  float acc[4][4] = {};
  for (int k = 0; k < 5; ++k) {
    const float* Wk = Wt + k * 65536;
    int t = t0 + ar + (k - 2);
    bool valid = (t >= 0) && (t < Trows);
    const float* Arow = Xbn + (size_t)(valid ? t : 0) * 256;
    for (int kb = 0; kb < 256; kb += 16) {
      float4 av = valid ? *(const float4*)(Arow + kb + ac) : make_float4(0.f, 0.f, 0.f, 0.f);
      As[ac + 0][ar] = av.x; As[ac + 1][ar] = av.y; As[ac + 2][ar] = av.z; As[ac + 3][ar] = av.w;
      *(float4*)&Ws[wr][wc] = *(const float4*)(Wk + (size_t)(kb + wr) * 256 + col0 + wc);
      __syncthreads();
#pragma unroll
      for (int kk = 0; kk < 16; ++kk) {
        float a[4], b[4];
#pragma unroll
        for (int i = 0; i < 4; ++i) a[i] = As[kk][ty * 4 + i];
#pragma unroll
        for (int j = 0; j < 4; ++j) b[j] = Ws[kk][tx * 4 + j];
#pragma unroll
        for (int i = 0; i < 4; ++i)
#pragma unroll
          for (int j = 0; j < 4; ++j) acc[i][j] = fmaf(a[i], b[j], acc[i][j]);
      }
      __syncthreads();
    }
  }
  float4 bv = *(const float4*)(bc + col0 + tx * 4);
#pragma unroll
  for (int i = 0; i < 4; i += 2) {
    float4 y0, y1;
    y0.x = fmaxf(acc[i][0] + bv.x, 0.f);
    y0.y = fmaxf(acc[i][1] + bv.y, 0.f);
    y0.z = fmaxf(acc[i][2] + bv.z, 0.f);
    y0.w = fmaxf(acc[i][3] + bv.w, 0.f);
    y1.x = fmaxf(acc[i + 1][0] + bv.x, 0.f);
    y1.y = fmaxf(acc[i + 1][1] + bv.y, 0.f);
    y1.z = fmaxf(acc[i + 1][2] + bv.z, 0.f);
    y1.w = fmaxf(acc[i + 1][3] + bv.w, 0.f);
    float4 p = f4max(y0, y1);
    int orow = (row0 + ty * 4 + i) >> 1;
    *(float4*)(Y + (size_t)orow * 256 + col0 + tx * 4) = p;
  }
}

extern "C" void kernel_launch(void* const* d_in, const int* in_sizes, int n_in,
                              void* d_out, int out_size, void* d_ws, size_t ws_size,
                              hipStream_t stream) {
  const float* data = (const float*)d_in[0];
  // d_in[1] all_ohs: unused by the 'fast' path
  const int* ei0 = (const int*)d_in[2];
  const int* ei1 = (const int*)d_in[3];
  const float* W0  = (const float*)d_in[4];
  const float* b0  = (const float*)d_in[5];
  const float* Wc0 = (const float*)d_in[6];
  const float* bc0 = (const float*)d_in[7];
  const float* W1  = (const float*)d_in[8];
  const float* b1  = (const float*)d_in[9];
  const float* Wc1 = (const float*)d_in[10];
  const float* bc1 = (const float*)d_in[11];
  float* out = (float*)d_out;

  float* ws = (float*)d_ws;
  size_t off = 0;
  auto alloc = [&](size_t n) { float* p = ws + off; off += (n + 63) & ~(size_t)63; return p; };
  float* X0  = alloc((size_t)NODE0 * Ff);   // X0; later reused as Y0 (16384*256, same size)
  float* Bm  = alloc((size_t)NODE0 * Hh);   // B0; later B1
  float* Mm  = alloc((size_t)NODE0 * Hh);   // M0; later M1
  float* X1  = alloc((size_t)NODE0 * Hh);   // X1; later X2
  float* Wd0 = alloc(128 * 256);
  float* Wd1 = alloc(256 * 256);
  float* Wt0 = alloc(5 * 256 * 256);
  float* Wt1 = alloc(5 * 256 * 256);
  int* ip = (int*)(ws + off);
  int* cnt0  = ip; ip += NODE0;
  int* cnt1  = ip; ip += NODE1;
  int* off0  = ip; ip += NODE0 + 1;
  int* cur0  = ip; ip += NODE0;
  int* srcs0 = ip; ip += E0;
  int* off1  = ip; ip += NODE1 + 1;
  int* cur1  = ip; ip += NODE1;
  int* srcs1 = ip; ip += E1;

  hipMemsetAsync(cnt0, 0, (NODE0 + NODE1) * sizeof(int), stream);

  k_perm<<<4096, 256, 0, stream>>>(data, X0);
  k_wd<<<128, 256, 0, stream>>>(W0, Wd0, 128);
  k_wd<<<256, 256, 0, stream>>>(W1, Wd1, 256);
  k_wt<<<1280, 256, 0, stream>>>(Wc0, Wt0);
  k_wt<<<1280, 256, 0, stream>>>(Wc1, Wt1);

  // ---- layer 0 ----
  k_count<<<E0 / 256, 256, 0, stream>>>(ei0 + E0, cnt0, E0);
  k_scan<<<1, 1024, 0, stream>>>(cnt0, off0, cur0, NODE0);
  k_fill<<<E0 / 256, 256, 0, stream>>>(ei0, ei0 + E0, cur0, srcs0, E0);
  k_gemm<false><<<dim3(NODE0 / 64, 4), 256, 0, stream>>>(X0, W0 + 128 * 256, Bm, 128, nullptr, nullptr);
  k_maxg<<<NODE0 / 4, 256, 0, stream>>>(Bm, off0, srcs0, Mm);
  k_gemm<true><<<dim3(NODE0 / 64, 4), 256, 0, stream>>>(X0, Wd0, X1, 128, b0, Mm);
  k_conv<<<dim3(NODE0 / 64, 4), 256, 0, stream>>>(X1, Wt0, bc0, X0 /*Y0*/, 128);

  // ---- layer 1 ----
  k_count<<<E1 / 256, 256, 0, stream>>>(ei1 + E1, cnt1, E1);
  k_scan<<<1, 1024, 0, stream>>>(cnt1, off1, cur1, NODE1);
  k_fill<<<E1 / 256, 256, 0, stream>>>(ei1, ei1 + E1, cur1, srcs1, E1);
  k_gemm<false><<<dim3(NODE1 / 64, 4), 256, 0, stream>>>(X0, W1 + 256 * 256, Bm, 256, nullptr, nullptr);
  k_maxg<<<NODE1 / 4, 256, 0, stream>>>(Bm, off1, srcs1, Mm);
  k_gemm<true><<<dim3(NODE1 / 64, 4), 256, 0, stream>>>(X0, Wd1, X1, 256, b1, Mm);
  k_conv<<<dim3(NODE1 / 64, 4), 256, 0, stream>>>(X1, Wt1, bc1, out, 64);
}

// Round 2
// 430.934 us; speedup vs baseline: 2.0713x; 2.0713x over previous
//
#include <hip/hip_runtime.h>
#include <hip/hip_bf16.h>
#include <math.h>

#define T0 128
#define BN 256           // B*N = 8*32
#define Ff 128
#define Hh 256
#define NODE0 32768      // BN*T0
#define E0 262144        // NODE0*8
#define T1 64
#define NODE1 16384      // BN*T1
#define E1 131072

typedef __attribute__((ext_vector_type(8))) short bhalf8;
typedef __attribute__((ext_vector_type(4))) float floatx4;

__device__ __forceinline__ unsigned short f2bf(float x) {
  union { float f; unsigned u; } v; v.f = x;
  unsigned r = v.u + 0x7fff + ((v.u >> 16) & 1);
  return (unsigned short)(r >> 16);
}
__device__ __forceinline__ float bf2f(unsigned short b) {
  union { unsigned u; float f; } v; v.u = ((unsigned)b) << 16;
  return v.f;
}

// ---------------- prep kernels ----------------

// data fp32 [T][BN][F] -> X0b bf16 [bn*T + t][F]
__global__ void k_permb(const float* __restrict__ src, unsigned short* __restrict__ dst) {
  int idx = blockIdx.x * 256 + threadIdx.x;   // NODE0 * 16 (8 elems each)
  int c8 = idx & 15;
  int r  = idx >> 4;
  int t  = r & (T0 - 1);
  int bn = r >> 7;
  const float* s = src + ((size_t)t * BN + bn) * Ff + c8 * 8;
  float4 a = *(const float4*)s;
  float4 b = *(const float4*)(s + 4);
  unsigned short o[8];
  o[0] = f2bf(a.x); o[1] = f2bf(a.y); o[2] = f2bf(a.z); o[3] = f2bf(a.w);
  o[4] = f2bf(b.x); o[5] = f2bf(b.y); o[6] = f2bf(b.z); o[7] = f2bf(b.w);
  *(int4*)(dst + ((size_t)(bn * T0 + t) * Ff + c8 * 8)) = *(int4*)o;
}

// W fp32 [2*half][256] -> Wbot_b[n][k], Wd_b[n][k] bf16 (n=0..255, k=0..half-1)
__global__ void k_wb(const float* __restrict__ W, unsigned short* __restrict__ Wbot_b,
                     unsigned short* __restrict__ Wd_b, int half, int kbits) {
  int idx = blockIdx.x * 256 + threadIdx.x;   // 256*half
  int n = idx >> kbits;
  int k = idx & (half - 1);
  float top = W[(size_t)k * 256 + n];
  float bot = W[(size_t)(half + k) * 256 + n];
  Wbot_b[idx] = f2bf(bot);
  Wd_b[idx]   = f2bf(top - bot);
}

// Wc fp32 [O=256][I=256][5] -> Wtb bf16 [tap][o][i]
__global__ void k_wtb(const float* __restrict__ Wc, unsigned short* __restrict__ Wtb) {
  int idx = blockIdx.x * 256 + threadIdx.x;   // 5*65536
  int tap = idx >> 16;
  int o = (idx >> 8) & 255;
  int i = idx & 255;
  Wtb[idx] = f2bf(Wc[((size_t)o * 256 + i) * 5 + tap]);
}

// ---------------- CSR build ----------------

__global__ void k_count(const int* __restrict__ dst, int* __restrict__ cnt, int E) {
  int e = blockIdx.x * 256 + threadIdx.x;
  if (e < E) atomicAdd(&cnt[dst[e]], 1);
}

__global__ __launch_bounds__(1024) void k_scan(const int* __restrict__ cnt, int* __restrict__ off,
                                               int* __restrict__ cur, int n) {
  __shared__ int part[1024];
  int tid = threadIdx.x;
  int chunk = n >> 10;
  int base = tid * chunk;
  int s = 0;
  for (int i = 0; i < chunk; ++i) s += cnt[base + i];
  part[tid] = s;
  __syncthreads();
  for (int d = 1; d < 1024; d <<= 1) {
    int v = (tid >= d) ? part[tid - d] : 0;
    __syncthreads();
    part[tid] += v;
    __syncthreads();
  }
  int run = (tid == 0) ? 0 : part[tid - 1];
  for (int i = 0; i < chunk; ++i) {
    off[base + i] = run;
    cur[base + i] = run;
    run += cnt[base + i];
  }
  if (tid == 1023) off[n] = run;
}

__global__ void k_fill(const int* __restrict__ srcIdx, const int* __restrict__ dstIdx,
                       int* __restrict__ cur, int* __restrict__ srcs, int E) {
  int e = blockIdx.x * 256 + threadIdx.x;
  if (e < E) {
    int p = atomicAdd(&cur[dstIdx[e]], 1);
    srcs[p] = srcIdx[e];
  }
}

// per-node segment max over bf16 rows of Bm [*,256]; writes Mm fp32
__global__ __launch_bounds__(256) void k_maxg(const unsigned short* __restrict__ Bm,
                                              const int* __restrict__ off,
                                              const int* __restrict__ srcs,
                                              float* __restrict__ Mm) {
  int node = blockIdx.x * 4 + (threadIdx.x >> 6);
  int lane = threadIdx.x & 63;
  int b = off[node], e = off[node + 1];
  float4 m = make_float4(-INFINITY, -INFINITY, -INFINITY, -INFINITY);
  for (int i = b; i < e; ++i) {
    int s = srcs[i];
    ushort4 v = *(const ushort4*)(Bm + (size_t)s * 256 + lane * 4);
    m.x = fmaxf(m.x, bf2f(v.x));
    m.y = fmaxf(m.y, bf2f(v.y));
    m.z = fmaxf(m.z, bf2f(v.z));
    m.w = fmaxf(m.w, bf2f(v.w));
  }
  *(float4*)(Mm + (size_t)node * 256 + lane * 4) = m;
}

// ---------------- MFMA GEMM ----------------
// C[M][256] = A[M][K](bf16) @ Wb^T  where Wb is [256][K] bf16 (n-major, k-contig)
// MODE 0: C = acc (bf16 out). MODE 1: C = relu(acc + bias + Mm) (bf16 out).
template <int MODE>
__global__ __launch_bounds__(256) void k_gemm(const unsigned short* __restrict__ A,
                                              const unsigned short* __restrict__ Wb,
                                              unsigned short* __restrict__ C, int K,
                                              const float* __restrict__ bias,
                                              const float* __restrict__ Mm) {
  __shared__ __align__(16) short A_lds[128 * 72];
  __shared__ __align__(16) short B_lds[128 * 72];
  int tid = threadIdx.x;
  int row0 = blockIdx.x * 128;
  int col0 = blockIdx.y * 128;
  int lane = tid & 63, wv = tid >> 6;
  int m16 = lane & 15, quad = lane >> 4;

  floatx4 acc[2][8];
#pragma unroll
  for (int mt = 0; mt < 2; ++mt)
#pragma unroll
    for (int nt = 0; nt < 8; ++nt) acc[mt][nt] = (floatx4){0.f, 0.f, 0.f, 0.f};

  for (int kb = 0; kb < K; kb += 64) {
    __syncthreads();
#pragma unroll
    for (int i = 0; i < 4; ++i) {
      int u = tid + i * 256;            // 128 rows x 8 segs
      int r = u >> 3, seg = u & 7;
      *(int4*)&A_lds[r * 72 + seg * 8] =
          *(const int4*)(A + (size_t)(row0 + r) * K + kb + seg * 8);
      *(int4*)&B_lds[r * 72 + seg * 8] =
          *(const int4*)(Wb + (size_t)(col0 + r) * K + kb + seg * 8);
    }
    __syncthreads();
#pragma unroll
    for (int ks = 0; ks < 2; ++ks) {
      bhalf8 a[2];
#pragma unroll
      for (int mt = 0; mt < 2; ++mt)
        a[mt] = *(const bhalf8*)&A_lds[(wv * 32 + mt * 16 + m16) * 72 + ks * 32 + quad * 8];
#pragma unroll
      for (int nt = 0; nt < 8; ++nt) {
        bhalf8 b = *(const bhalf8*)&B_lds[(nt * 16 + m16) * 72 + ks * 32 + quad * 8];
#pragma unroll
        for (int mt = 0; mt < 2; ++mt)
          acc[mt][nt] = __builtin_amdgcn_mfma_f32_16x16x32_bf16(a[mt], b, acc[mt][nt], 0, 0, 0);
      }
    }
  }

#pragma unroll
  for (int mt = 0; mt < 2; ++mt) {
    int g0 = row0 + wv * 32 + mt * 16 + quad * 4;
#pragma unroll
    for (int nt = 0; nt < 8; ++nt) {
      int c = col0 + nt * 16 + m16;
      float bv = (MODE == 1) ? bias[c] : 0.f;
#pragma unroll
      for (int r = 0; r < 4; ++r) {
        float v = acc[mt][nt][r];
        if (MODE == 1) v = fmaxf(v + bv + Mm[(size_t)(g0 + r) * 256 + c], 0.f);
        C[(size_t)(g0 + r) * 256 + c] = f2bf(v);
      }
    }
  }
}

// ---------------- MFMA temporal conv ----------------
// Y = maxpool2(relu(conv1d(X, Wtb, k=5, pad=2) + bc)); X bf16 [M][256] viewed [BN][Trows][256]
// block tile: 64 rows x 128 cols; A window staged once per K-chunk, reused across taps.
template <bool OUT_F32>
__global__ __launch_bounds__(256) void k_conv(const unsigned short* __restrict__ X,
                                              const unsigned short* __restrict__ Wtb,
                                              const float* __restrict__ bc,
                                              void* __restrict__ Yout, int Trows) {
  __shared__ __align__(16) short A_lds[68 * 72];
  __shared__ __align__(16) short B_lds[128 * 72];
  int tid = threadIdx.x;
  int row0 = blockIdx.x * 64;
  int col0 = blockIdx.y * 128;
  int lane = tid & 63, wv = tid >> 6;
  int m16 = lane & 15, quad = lane >> 4;
  int t0 = row0 % Trows;

  floatx4 acc[8];
#pragma unroll
  for (int nt = 0; nt < 8; ++nt) acc[nt] = (floatx4){0.f, 0.f, 0.f, 0.f};

  for (int kb = 0; kb < 256; kb += 64) {
    __syncthreads();
    // stage A window: rows [row0-2, row0+66), zero outside [0,Trows) of this bn
    for (int u = tid; u < 68 * 8; u += 256) {
      int r = u >> 3, seg = u & 7;
      int tt = t0 + r - 2;
      int4 v = {0, 0, 0, 0};
      if (tt >= 0 && tt < Trows)
        v = *(const int4*)(X + (size_t)(row0 + r - 2) * 256 + kb + seg * 8);
      *(int4*)&A_lds[r * 72 + seg * 8] = v;
    }
    for (int tap = 0; tap < 5; ++tap) {
      if (tap > 0) __syncthreads();
      const unsigned short* Wk = Wtb + (size_t)tap * 65536;
#pragma unroll
      for (int i = 0; i < 4; ++i) {
        int u = tid + i * 256;          // 128 rows x 8 segs
        int r = u >> 3, seg = u & 7;
        *(int4*)&B_lds[r * 72 + seg * 8] =
            *(const int4*)(Wk + (size_t)(col0 + r) * 256 + kb + seg * 8);
      }
      __syncthreads();
#pragma unroll
      for (int ks = 0; ks < 2; ++ks) {
        bhalf8 a = *(const bhalf8*)&A_lds[(wv * 16 + m16 + tap) * 72 + ks * 32 + quad * 8];
#pragma unroll
        for (int nt = 0; nt < 8; ++nt) {
          bhalf8 b = *(const bhalf8*)&B_lds[(nt * 16 + m16) * 72 + ks * 32 + quad * 8];
          acc[nt] = __builtin_amdgcn_mfma_f32_16x16x32_bf16(a, b, acc[nt], 0, 0, 0);
        }
      }
    }
  }

  int gbase = row0 + wv * 16 + quad * 4;
#pragma unroll
  for (int nt = 0; nt < 8; ++nt) {
    int c = col0 + nt * 16 + m16;
    float bv = bc[c];
    float y0 = fmaxf(acc[nt][0] + bv, 0.f);
    float y1 = fmaxf(acc[nt][1] + bv, 0.f);
    float y2 = fmaxf(acc[nt][2] + bv, 0.f);
    float y3 = fmaxf(acc[nt][3] + bv, 0.f);
    float p0 = fmaxf(y0, y1);
    float p1 = fmaxf(y2, y3);
    int o0 = gbase >> 1;
    if (OUT_F32) {
      float* Y = (float*)Yout;
      Y[(size_t)o0 * 256 + c] = p0;
      Y[(size_t)(o0 + 1) * 256 + c] = p1;
    } else {
      unsigned short* Y = (unsigned short*)Yout;
      Y[(size_t)o0 * 256 + c] = f2bf(p0);
      Y[(size_t)(o0 + 1) * 256 + c] = f2bf(p1);
    }
  }
}

extern "C" void kernel_launch(void* const* d_in, const int* in_sizes, int n_in,
                              void* d_out, int out_size, void* d_ws, size_t ws_size,
                              hipStream_t stream) {
  const float* data = (const float*)d_in[0];
  const int* ei0 = (const int*)d_in[2];
  const int* ei1 = (const int*)d_in[3];
  const float* W0  = (const float*)d_in[4];
  const float* b0  = (const float*)d_in[5];
  const float* Wc0 = (const float*)d_in[6];
  const float* bc0 = (const float*)d_in[7];
  const float* W1  = (const float*)d_in[8];
  const float* b1  = (const float*)d_in[9];
  const float* Wc1 = (const float*)d_in[10];
  const float* bc1 = (const float*)d_in[11];
  float* out = (float*)d_out;

  char* base = (char*)d_ws;
  size_t off = 0;
  auto alloc = [&](size_t bytes) { void* p = base + off; off += (bytes + 255) & ~(size_t)255; return p; };
  unsigned short* X0b   = (unsigned short*)alloc((size_t)NODE0 * Ff * 2);
  unsigned short* Bm    = (unsigned short*)alloc((size_t)NODE0 * Hh * 2);
  float*          Mm    = (float*)alloc((size_t)NODE0 * Hh * 4);
  unsigned short* X1b   = (unsigned short*)alloc((size_t)NODE0 * Hh * 2);
  unsigned short* Y0b   = (unsigned short*)alloc((size_t)NODE1 * Hh * 2);
  unsigned short* Wbot0 = (unsigned short*)alloc(256 * 128 * 2);
  unsigned short* Wd0   = (unsigned short*)alloc(256 * 128 * 2);
  unsigned short* Wbot1 = (unsigned short*)alloc(256 * 256 * 2);
  unsigned short* Wd1   = (unsigned short*)alloc(256 * 256 * 2);
  unsigned short* Wtb0  = (unsigned short*)alloc(5 * 65536 * 2);
  unsigned short* Wtb1  = (unsigned short*)alloc(5 * 65536 * 2);
  int* cnt0  = (int*)alloc(NODE0 * 4);
  int* cnt1  = (int*)alloc(NODE1 * 4);
  int* off0  = (int*)alloc((NODE0 + 1) * 4);
  int* cur0  = (int*)alloc(NODE0 * 4);
  int* srcs0 = (int*)alloc(E0 * 4);
  int* off1  = (int*)alloc((NODE1 + 1) * 4);
  int* cur1  = (int*)alloc(NODE1 * 4);
  int* srcs1 = (int*)alloc(E1 * 4);

  hipMemsetAsync(cnt0, 0, NODE0 * sizeof(int), stream);
  hipMemsetAsync(cnt1, 0, NODE1 * sizeof(int), stream);

  k_permb<<<NODE0 * 16 / 256, 256, 0, stream>>>(data, X0b);
  k_wb<<<256 * 128 / 256, 256, 0, stream>>>(W0, Wbot0, Wd0, 128, 7);
  k_wb<<<256 * 256 / 256, 256, 0, stream>>>(W1, Wbot1, Wd1, 256, 8);
  k_wtb<<<5 * 65536 / 256, 256, 0, stream>>>(Wc0, Wtb0);
  k_wtb<<<5 * 65536 / 256, 256, 0, stream>>>(Wc1, Wtb1);

  // ---- layer 0 ----
  k_count<<<E0 / 256, 256, 0, stream>>>(ei0 + E0, cnt0, E0);
  k_scan<<<1, 1024, 0, stream>>>(cnt0, off0, cur0, NODE0);
  k_fill<<<E0 / 256, 256, 0, stream>>>(ei0, ei0 + E0, cur0, srcs0, E0);
  k_gemm<0><<<dim3(NODE0 / 128, 2), 256, 0, stream>>>(X0b, Wbot0, Bm, 128, nullptr, nullptr);
  k_maxg<<<NODE0 / 4, 256, 0, stream>>>(Bm, off0, srcs0, Mm);
  k_gemm<1><<<dim3(NODE0 / 128, 2), 256, 0, stream>>>(X0b, Wd0, X1b, 128, b0, Mm);
  k_conv<false><<<dim3(NODE0 / 64, 2), 256, 0, stream>>>(X1b, Wtb0, bc0, Y0b, 128);

  // ---- layer 1 ----
  k_count<<<E1 / 256, 256, 0, stream>>>(ei1 + E1, cnt1, E1);
  k_scan<<<1, 1024, 0, stream>>>(cnt1, off1, cur1, NODE1);
  k_fill<<<E1 / 256, 256, 0, stream>>>(ei1, ei1 + E1, cur1, srcs1, E1);
  k_gemm<0><<<dim3(NODE1 / 128, 2), 256, 0, stream>>>(Y0b, Wbot1, Bm, 256, nullptr, nullptr);
  k_maxg<<<NODE1 / 4, 256, 0, stream>>>(Bm, off1, srcs1, Mm);
  k_gemm<1><<<dim3(NODE1 / 128, 2), 256, 0, stream>>>(Y0b, Wd1, X1b, 256, b1, Mm);
  k_conv<true><<<dim3(NODE1 / 64, 2), 256, 0, stream>>>(X1b, Wtb1, bc1, out, 64);
}

// Round 4
// 265.040 us; speedup vs baseline: 3.3677x; 1.6259x over previous
//
#include <hip/hip_runtime.h>
#include <hip/hip_bf16.h>
#include <math.h>

#define T0 128
#define BN 256           // B*N = 8*32
#define Ff 128
#define Hh 256
#define NODE0 32768      // BN*T0
#define E0 262144        // NODE0*8
#define T1 64
#define NODE1 16384      // BN*T1
#define E1 131072
#define CAP 48           // per-node in-edge capacity; deg ~ Poisson(8), P(>48) ~ 1e-25

typedef __attribute__((ext_vector_type(8))) short bhalf8;
typedef __attribute__((ext_vector_type(4))) float floatx4;

__device__ __forceinline__ unsigned short f2bf(float x) {
  union { float f; unsigned u; } v; v.f = x;
  unsigned r = v.u + 0x7fff + ((v.u >> 16) & 1);
  return (unsigned short)(r >> 16);
}
__device__ __forceinline__ float bf2f(unsigned short b) {
  union { unsigned u; float f; } v; v.u = ((unsigned)b) << 16;
  return v.f;
}

// ---------------- prep kernels ----------------

// data fp32 [T][BN][F] -> X0b bf16 [bn*T + t][F]
__global__ void k_permb(const float* __restrict__ src, unsigned short* __restrict__ dst) {
  int idx = blockIdx.x * 256 + threadIdx.x;   // NODE0 * 16 (8 elems each)
  int c8 = idx & 15;
  int r  = idx >> 4;
  int t  = r & (T0 - 1);
  int bn = r >> 7;
  const float* s = src + ((size_t)t * BN + bn) * Ff + c8 * 8;
  float4 a = *(const float4*)s;
  float4 b = *(const float4*)(s + 4);
  unsigned short o[8];
  o[0] = f2bf(a.x); o[1] = f2bf(a.y); o[2] = f2bf(a.z); o[3] = f2bf(a.w);
  o[4] = f2bf(b.x); o[5] = f2bf(b.y); o[6] = f2bf(b.z); o[7] = f2bf(b.w);
  *(int4*)(dst + ((size_t)(bn * T0 + t) * Ff + c8 * 8)) = *(int4*)o;
}

// W fp32 [2*half][256] -> Wbot_b[n][k], Wd_b[n][k] bf16 (n=0..255, k=0..half-1)
__global__ void k_wb(const float* __restrict__ W, unsigned short* __restrict__ Wbot_b,
                     unsigned short* __restrict__ Wd_b, int half, int kbits) {
  int idx = blockIdx.x * 256 + threadIdx.x;   // 256*half
  int n = idx >> kbits;
  int k = idx & (half - 1);
  float top = W[(size_t)k * 256 + n];
  float bot = W[(size_t)(half + k) * 256 + n];
  Wbot_b[idx] = f2bf(bot);
  Wd_b[idx]   = f2bf(top - bot);
}

// Wc fp32 [O=256][I=256][5] -> Wtb bf16 [tap][o][i]
__global__ void k_wtb(const float* __restrict__ Wc, unsigned short* __restrict__ Wtb) {
  int idx = blockIdx.x * 256 + threadIdx.x;   // 5*65536
  int tap = idx >> 16;
  int o = (idx >> 8) & 255;
  int i = idx & 255;
  Wtb[idx] = f2bf(Wc[((size_t)o * 256 + i) * 5 + tap]);
}

// ---------------- bucketed edge fill (no CSR scan) ----------------

__global__ void k_fill(const int* __restrict__ srcIdx, const int* __restrict__ dstIdx,
                       int* __restrict__ cnt, int* __restrict__ slot, int E) {
  int e = blockIdx.x * 256 + threadIdx.x;
  if (e < E) {
    int d = dstIdx[e];
    int p = atomicAdd(&cnt[d], 1);
    if (p < CAP) slot[(size_t)d * CAP + p] = srcIdx[e];
  }
}

// per-node segment max over bf16 rows of Bm [*,256]; writes Mm bf16.
// Empty segments stay -inf (bf16 0xFF80): the gemm epilogue's relu turns
// relu(A + b + (-inf)) into 0, exactly matching PyG's isneginf->0 fill.
__global__ __launch_bounds__(256) void k_maxg(const unsigned short* __restrict__ Bm,
                                              const int* __restrict__ cnt,
                                              const int* __restrict__ slot,
                                              unsigned short* __restrict__ Mm) {
  int node = blockIdx.x * 4 + (threadIdx.x >> 6);
  int lane = threadIdx.x & 63;
  int n = cnt[node];
  if (n > CAP) n = CAP;
  const int* sl = slot + (size_t)node * CAP;
  float4 m = make_float4(-INFINITY, -INFINITY, -INFINITY, -INFINITY);
  int i = 0;
  for (; i + 4 <= n; i += 4) {
    int s0 = sl[i], s1 = sl[i + 1], s2 = sl[i + 2], s3 = sl[i + 3];
    ushort4 v0 = *(const ushort4*)(Bm + (size_t)s0 * 256 + lane * 4);
    ushort4 v1 = *(const ushort4*)(Bm + (size_t)s1 * 256 + lane * 4);
    ushort4 v2 = *(const ushort4*)(Bm + (size_t)s2 * 256 + lane * 4);
    ushort4 v3 = *(const ushort4*)(Bm + (size_t)s3 * 256 + lane * 4);
    m.x = fmaxf(fmaxf(fmaxf(m.x, bf2f(v0.x)), fmaxf(bf2f(v1.x), bf2f(v2.x))), bf2f(v3.x));
    m.y = fmaxf(fmaxf(fmaxf(m.y, bf2f(v0.y)), fmaxf(bf2f(v1.y), bf2f(v2.y))), bf2f(v3.y));
    m.z = fmaxf(fmaxf(fmaxf(m.z, bf2f(v0.z)), fmaxf(bf2f(v1.z), bf2f(v2.z))), bf2f(v3.z));
    m.w = fmaxf(fmaxf(fmaxf(m.w, bf2f(v0.w)), fmaxf(bf2f(v1.w), bf2f(v2.w))), bf2f(v3.w));
  }
  for (; i < n; ++i) {
    int s = sl[i];
    ushort4 v = *(const ushort4*)(Bm + (size_t)s * 256 + lane * 4);
    m.x = fmaxf(m.x, bf2f(v.x));
    m.y = fmaxf(m.y, bf2f(v.y));
    m.z = fmaxf(m.z, bf2f(v.z));
    m.w = fmaxf(m.w, bf2f(v.w));
  }
  ushort4 o;
  o.x = f2bf(m.x); o.y = f2bf(m.y); o.z = f2bf(m.z); o.w = f2bf(m.w);
  *(ushort4*)(Mm + (size_t)node * 256 + lane * 4) = o;
}

// ---------------- MFMA GEMM ----------------
// C[M][256] = A[M][K](bf16) @ Wb^T  where Wb is [256][K] bf16 (n-major, k-contig)
// MODE 0: C = acc (bf16 out). MODE 1: C = relu(acc + bias + Mm) (bf16 out).
template <int MODE>
__global__ __launch_bounds__(256) void k_gemm(const unsigned short* __restrict__ A,
                                              const unsigned short* __restrict__ Wb,
                                              unsigned short* __restrict__ C, int K,
                                              const float* __restrict__ bias,
                                              const unsigned short* __restrict__ Mm) {
  __shared__ __align__(16) short A_lds[128 * 72];
  __shared__ __align__(16) short B_lds[128 * 72];
  int tid = threadIdx.x;
  int row0 = blockIdx.x * 128;
  int col0 = blockIdx.y * 128;
  int lane = tid & 63, wv = tid >> 6;
  int m16 = lane & 15, quad = lane >> 4;

  floatx4 acc[2][8];
#pragma unroll
  for (int mt = 0; mt < 2; ++mt)
#pragma unroll
    for (int nt = 0; nt < 8; ++nt) acc[mt][nt] = (floatx4){0.f, 0.f, 0.f, 0.f};

  for (int kb = 0; kb < K; kb += 64) {
    __syncthreads();
#pragma unroll
    for (int i = 0; i < 4; ++i) {
      int u = tid + i * 256;            // 128 rows x 8 segs
      int r = u >> 3, seg = u & 7;
      *(int4*)&A_lds[r * 72 + seg * 8] =
          *(const int4*)(A + (size_t)(row0 + r) * K + kb + seg * 8);
      *(int4*)&B_lds[r * 72 + seg * 8] =
          *(const int4*)(Wb + (size_t)(col0 + r) * K + kb + seg * 8);
    }
    __syncthreads();
#pragma unroll
    for (int ks = 0; ks < 2; ++ks) {
      bhalf8 a[2];
#pragma unroll
      for (int mt = 0; mt < 2; ++mt)
        a[mt] = *(const bhalf8*)&A_lds[(wv * 32 + mt * 16 + m16) * 72 + ks * 32 + quad * 8];
#pragma unroll
      for (int nt = 0; nt < 8; ++nt) {
        bhalf8 b = *(const bhalf8*)&B_lds[(nt * 16 + m16) * 72 + ks * 32 + quad * 8];
#pragma unroll
        for (int mt = 0; mt < 2; ++mt)
          acc[mt][nt] = __builtin_amdgcn_mfma_f32_16x16x32_bf16(a[mt], b, acc[mt][nt], 0, 0, 0);
      }
    }
  }

#pragma unroll
  for (int mt = 0; mt < 2; ++mt) {
    int g0 = row0 + wv * 32 + mt * 16 + quad * 4;
#pragma unroll
    for (int nt = 0; nt < 8; ++nt) {
      int c = col0 + nt * 16 + m16;
      float bv = (MODE == 1) ? bias[c] : 0.f;
#pragma unroll
      for (int r = 0; r < 4; ++r) {
        float v = acc[mt][nt][r];
        if (MODE == 1) v = fmaxf(v + bv + bf2f(Mm[(size_t)(g0 + r) * 256 + c]), 0.f);
        C[(size_t)(g0 + r) * 256 + c] = f2bf(v);
      }
    }
  }
}

// ---------------- MFMA temporal conv ----------------
// Y = maxpool2(relu(conv1d(X, Wtb, k=5, pad=2) + bc)); X bf16 [M][256] viewed [BN][TR][256]
// One block per (bn, col-half): TR rows x 128 cols; A window staged once per K-chunk,
// reused across all 5 taps (tap shift = LDS row offset).
template <int TR, bool OUT_F32>
__global__ __launch_bounds__(256) void k_conv(const unsigned short* __restrict__ X,
                                              const unsigned short* __restrict__ Wtb,
                                              const float* __restrict__ bc,
                                              void* __restrict__ Yout) {
  const int MT = TR / 64;                      // 16-row MFMA tiles per wave
  __shared__ __align__(16) short A_lds[(TR + 4) * 72];
  __shared__ __align__(16) short B_lds[128 * 72];
  int tid = threadIdx.x;
  int row0 = blockIdx.x * TR;                  // one bn per block
  int col0 = blockIdx.y * 128;
  int lane = tid & 63, wv = tid >> 6;
  int m16 = lane & 15, quad = lane >> 4;

  floatx4 acc[MT][8];
#pragma unroll
  for (int mt = 0; mt < MT; ++mt)
#pragma unroll
    for (int nt = 0; nt < 8; ++nt) acc[mt][nt] = (floatx4){0.f, 0.f, 0.f, 0.f};

  for (int kb = 0; kb < 256; kb += 64) {
    __syncthreads();
    // stage A window: bn-local rows [-2, TR+2), zero-padded
    for (int u = tid; u < (TR + 4) * 8; u += 256) {
      int r = u >> 3, seg = u & 7;
      int tt = r - 2;
      int4 v = {0, 0, 0, 0};
      if (tt >= 0 && tt < TR)
        v = *(const int4*)(X + (size_t)(row0 + tt) * 256 + kb + seg * 8);
      *(int4*)&A_lds[r * 72 + seg * 8] = v;
    }
    for (int tap = 0; tap < 5; ++tap) {
      if (tap > 0) __syncthreads();
      const unsigned short* Wk = Wtb + (size_t)tap * 65536;
#pragma unroll
      for (int i = 0; i < 4; ++i) {
        int u = tid + i * 256;          // 128 rows x 8 segs
        int r = u >> 3, seg = u & 7;
        *(int4*)&B_lds[r * 72 + seg * 8] =
            *(const int4*)(Wk + (size_t)(col0 + r) * 256 + kb + seg * 8);
      }
      __syncthreads();
#pragma unroll
      for (int ks = 0; ks < 2; ++ks) {
        bhalf8 a[MT];
#pragma unroll
        for (int mt = 0; mt < MT; ++mt)
          a[mt] = *(const bhalf8*)&A_lds[(wv * (16 * MT) + mt * 16 + m16 + tap) * 72 + ks * 32 + quad * 8];
#pragma unroll
        for (int nt = 0; nt < 8; ++nt) {
          bhalf8 b = *(const bhalf8*)&B_lds[(nt * 16 + m16) * 72 + ks * 32 + quad * 8];
#pragma unroll
          for (int mt = 0; mt < MT; ++mt)
            acc[mt][nt] = __builtin_amdgcn_mfma_f32_16x16x32_bf16(a[mt], b, acc[mt][nt], 0, 0, 0);
        }
      }
    }
  }

#pragma unroll
  for (int mt = 0; mt < MT; ++mt) {
    int gbase = row0 + wv * (16 * MT) + mt * 16 + quad * 4;
#pragma unroll
    for (int nt = 0; nt < 8; ++nt) {
      int c = col0 + nt * 16 + m16;
      float bv = bc[c];
      float y0 = fmaxf(acc[mt][nt][0] + bv, 0.f);
      float y1 = fmaxf(acc[mt][nt][1] + bv, 0.f);
      float y2 = fmaxf(acc[mt][nt][2] + bv, 0.f);
      float y3 = fmaxf(acc[mt][nt][3] + bv, 0.f);
      float p0 = fmaxf(y0, y1);
      float p1 = fmaxf(y2, y3);
      int o0 = gbase >> 1;
      if (OUT_F32) {
        float* Y = (float*)Yout;
        Y[(size_t)o0 * 256 + c] = p0;
        Y[(size_t)(o0 + 1) * 256 + c] = p1;
      } else {
        unsigned short* Y = (unsigned short*)Yout;
        Y[(size_t)o0 * 256 + c] = f2bf(p0);
        Y[(size_t)(o0 + 1) * 256 + c] = f2bf(p1);
      }
    }
  }
}

extern "C" void kernel_launch(void* const* d_in, const int* in_sizes, int n_in,
                              void* d_out, int out_size, void* d_ws, size_t ws_size,
                              hipStream_t stream) {
  const float* data = (const float*)d_in[0];
  const int* ei0 = (const int*)d_in[2];
  const int* ei1 = (const int*)d_in[3];
  const float* W0  = (const float*)d_in[4];
  const float* b0  = (const float*)d_in[5];
  const float* Wc0 = (const float*)d_in[6];
  const float* bc0 = (const float*)d_in[7];
  const float* W1  = (const float*)d_in[8];
  const float* b1  = (const float*)d_in[9];
  const float* Wc1 = (const float*)d_in[10];
  const float* bc1 = (const float*)d_in[11];
  float* out = (float*)d_out;

  char* base = (char*)d_ws;
  size_t off = 0;
  auto alloc = [&](size_t bytes) { void* p = base + off; off += (bytes + 255) & ~(size_t)255; return p; };
  unsigned short* X0b   = (unsigned short*)alloc((size_t)NODE0 * Ff * 2);
  unsigned short* Bm    = (unsigned short*)alloc((size_t)NODE0 * Hh * 2);
  unsigned short* Mm    = (unsigned short*)alloc((size_t)NODE0 * Hh * 2);
  unsigned short* X1b   = (unsigned short*)alloc((size_t)NODE0 * Hh * 2);
  unsigned short* Y0b   = (unsigned short*)alloc((size_t)NODE1 * Hh * 2);
  unsigned short* Wbot0 = (unsigned short*)alloc(256 * 128 * 2);
  unsigned short* Wd0   = (unsigned short*)alloc(256 * 128 * 2);
  unsigned short* Wbot1 = (unsigned short*)alloc(256 * 256 * 2);
  unsigned short* Wd1   = (unsigned short*)alloc(256 * 256 * 2);
  unsigned short* Wtb0  = (unsigned short*)alloc(5 * 65536 * 2);
  unsigned short* Wtb1  = (unsigned short*)alloc(5 * 65536 * 2);
  int* cnt0  = (int*)alloc(NODE0 * 4);
  int* cnt1  = (int*)alloc(NODE1 * 4);
  int* slot0 = (int*)alloc((size_t)NODE0 * CAP * 4);
  int* slot1 = (int*)alloc((size_t)NODE1 * CAP * 4);

  hipMemsetAsync(cnt0, 0, NODE0 * sizeof(int), stream);
  hipMemsetAsync(cnt1, 0, NODE1 * sizeof(int), stream);

  k_permb<<<NODE0 * 16 / 256, 256, 0, stream>>>(data, X0b);
  k_wb<<<256 * 128 / 256, 256, 0, stream>>>(W0, Wbot0, Wd0, 128, 7);
  k_wb<<<256 * 256 / 256, 256, 0, stream>>>(W1, Wbot1, Wd1, 256, 8);
  k_wtb<<<5 * 65536 / 256, 256, 0, stream>>>(Wc0, Wtb0);
  k_wtb<<<5 * 65536 / 256, 256, 0, stream>>>(Wc1, Wtb1);

  // ---- layer 0 ----
  k_fill<<<E0 / 256, 256, 0, stream>>>(ei0, ei0 + E0, cnt0, slot0, E0);
  k_gemm<0><<<dim3(NODE0 / 128, 2), 256, 0, stream>>>(X0b, Wbot0, Bm, 128, nullptr, nullptr);
  k_maxg<<<NODE0 / 4, 256, 0, stream>>>(Bm, cnt0, slot0, Mm);
  k_gemm<1><<<dim3(NODE0 / 128, 2), 256, 0, stream>>>(X0b, Wd0, X1b, 128, b0, Mm);
  k_conv<128, false><<<dim3(BN, 2), 256, 0, stream>>>(X1b, Wtb0, bc0, Y0b);

  // ---- layer 1 ----
  k_fill<<<E1 / 256, 256, 0, stream>>>(ei1, ei1 + E1, cnt1, slot1, E1);
  k_gemm<0><<<dim3(NODE1 / 128, 2), 256, 0, stream>>>(Y0b, Wbot1, Bm, 256, nullptr, nullptr);
  k_maxg<<<NODE1 / 4, 256, 0, stream>>>(Bm, cnt1, slot1, Mm);
  k_gemm<1><<<dim3(NODE1 / 128, 2), 256, 0, stream>>>(Y0b, Wd1, X1b, 256, b1, Mm);
  k_conv<64, true><<<dim3(BN, 2), 256, 0, stream>>>(X1b, Wtb1, bc1, out);
}